// Round 11
// baseline (106.747 us; speedup 1.0000x reference)
//
#include <hip/hip_runtime.h>

#define S_ROWS 2048
#define RO_ROWS 8192
#define HEADS 8
#define HDIM 32
#define ROWLEN 256           // HEADS * HDIM
#define NB_S (S_ROWS / 16)   // 128 fragment-blocks of s
#define NB_RO (RO_ROWS / 16) // 512 fragment-blocks of ro

typedef __attribute__((ext_vector_type(8))) short bf16x8;
typedef __attribute__((ext_vector_type(4))) float f32x4;
typedef __attribute__((ext_vector_type(4))) short s16x4;

__device__ __forceinline__ short f32_to_bf16_rne(float f) {
    union { float f; unsigned u; } v; v.f = f;
    return (short)((v.u + 0x7fffu + ((v.u >> 16) & 1u)) >> 16);
}

// Normalize every 32-elem head vector; emit bf16 fragments in LANE-LINEAR
// MFMA order: fragment (h, nb) is 1 KiB where byte offset lane*16 holds the
// 8 bf16 that MFMA lane `lane` consumes (row = lane&15, k = (lane>>4)*8..+7).
// Dist then loads operands as frag_base + lane*16B — fully coalesced 1 KiB
// per wave-instruction.
__global__ __launch_bounds__(256) void mhd_normalize(const float* __restrict__ s,
                                                     const float* __restrict__ ro,
                                                     short* __restrict__ sF,
                                                     short* __restrict__ roF) {
    const int v   = blockIdx.x * 256 + threadIdx.x;  // vec4-element id
    const int dg  = v & 7;            // k-elems dg*4 .. dg*4+3
    const int r16 = (v >> 3) & 15;    // row within fragment block
    const int u   = v >> 7;           // (h, nb) chunk id
    const int h   = u & 7;
    const int nb_all = u >> 3;        // 0..639
    const bool isS = nb_all < NB_S;
    const int nb  = isS ? nb_all : nb_all - NB_S;
    const int n   = nb * 16 + r16;    // source row within its tensor

    const float* src = isS ? s : ro;
    f32x4 x = *(const f32x4*)(src + (size_t)n * ROWLEN + h * HDIM + dg * 4);
    float ss = x[0] * x[0] + x[1] * x[1] + x[2] * x[2] + x[3] * x[3];
    ss += __shfl_xor(ss, 1);
    ss += __shfl_xor(ss, 2);
    ss += __shfl_xor(ss, 4);
    const float inv = rsqrtf(ss);
    s16x4 r;
    r[0] = f32_to_bf16_rne(x[0] * inv);
    r[1] = f32_to_bf16_rne(x[1] * inv);
    r[2] = f32_to_bf16_rne(x[2] * inv);
    r[3] = f32_to_bf16_rne(x[3] * inv);

    short* dst = isS ? sF : roF;
    const int NB = isS ? NB_S : NB_RO;
    // lane-linear: lane = (dg>>1)*16 + r16, 16B half = dg&1
    const int lane_in_frag = ((dg >> 1) << 4) + r16;
    const size_t off = ((size_t)(h * NB + nb) << 9) + lane_in_frag * 8 + (dg & 1) * 4;
    *(s16x4*)(dst + off) = r;
}

// Store-streaming variant of the XCD-strip design (tests the phase-overlap
// theory, unconfounded by R5's B-resident register pressure):
// loop the 4 output row-chunks OUTERMOST; per (i,h) reload 1 A-frag + 4
// B-frags (B re-read 4x, from L2/L3), 4 MFMAs; store chunk i immediately
// after its 8 heads -> the 64 MiB write stream is spread over the whole
// kernel instead of a terminal burst (posted writes drain under compute).
// Live regs: rmax 16 + a 4 + b 16 + addr -> ~70 VGPR.
// Geometry unchanged from R10: bid&7 -> XCD strip (s-strip L2-resident),
// bid>>3 -> col tile; block 256x128, 8 waves (4x2 of 64x64).
// mfma(B, A): D lane-axis (lane&15) = s-row, reg-axis = 4 consecutive
// ro-cols. Epilogue per chunk repacks via per-wave padded LDS so each store
// instr covers 4 rows x 256B (proven R4/R9/R10 epilogue).
__global__ __launch_bounds__(512, 4) void mhd_dist(const short* __restrict__ sF,
                                                   const short* __restrict__ roF,
                                                   float* __restrict__ out) {
    __shared__ float elds[8][16][68];     // per-wave repack, 34.8 KiB
    const int lane = threadIdx.x & 63;
    const int wave = threadIdx.x >> 6;    // 0..7
    const int wr = wave >> 1;             // 0..3: 64-row strip in block
    const int wc = wave & 1;              // 0..1: 64-col strip in block
    const int xcd = blockIdx.x & 7;       // strip id == XCD (heuristic)
    const int q   = blockIdx.x >> 3;      // 0..63: col tile of 128
    const int nbA = xcd * 16 + wr * 4;    // first s fragment-block
    const int nbB = q * 8 + wc * 4;       // first ro fragment-block
    const size_t laneOff = (size_t)lane * 8;   // shorts: lane*16B

    const int l15 = lane & 15;
    const int kg = lane >> 4;
    float* outBase = out + (size_t)(xcd * 256 + wr * 64) * RO_ROWS
                         + q * 128 + wc * 64;
    const int srow = lane >> 4;        // 0..3: row within a 4-row store group
    const int scol = (lane & 15) * 4;  // f32 col within the 64-wide tile

#pragma unroll 1
    for (int i = 0; i < 4; ++i) {
        f32x4 rmax[4];
#pragma unroll
        for (int j = 0; j < 4; ++j)
            rmax[j] = (f32x4){-3.0e38f, -3.0e38f, -3.0e38f, -3.0e38f};

#pragma unroll 1
        for (int h = 0; h < HEADS; ++h) {
            const bf16x8 a = *(const bf16x8*)(
                sF + ((size_t)(h * NB_S + nbA + i) << 9) + laneOff);
            const short* bBase = roF + ((size_t)(h * NB_RO + nbB) << 9) + laneOff;
            bf16x8 b[4];
#pragma unroll
            for (int j = 0; j < 4; ++j)
                b[j] = *(const bf16x8*)(bBase + ((size_t)j << 9));
#pragma unroll
            for (int j = 0; j < 4; ++j) {
                f32x4 acc = {0.f, 0.f, 0.f, 0.f};
                acc = __builtin_amdgcn_mfma_f32_16x16x32_bf16(b[j], a, acc, 0, 0, 0);
#pragma unroll
                for (int q2 = 0; q2 < 4; ++q2)
                    rmax[j][q2] = fmaxf(rmax[j][q2], acc[q2]);
            }
        }

        // stream chunk i: repack via wave-private LDS (same-wave lgkmcnt
        // ordering, no barriers), then 4 store instrs of 4 rows x 256B
#pragma unroll
        for (int j = 0; j < 4; ++j)
            *(f32x4*)&elds[wave][l15][kg * 4 + j * 16] = rmax[j];
#pragma unroll
        for (int t = 0; t < 4; ++t) {
            const int rowL = t * 4 + srow;
            f32x4 vv = *(const f32x4*)&elds[wave][rowL][scol];
            *(f32x4*)(outBase + (size_t)(i * 16 + rowL) * RO_ROWS + scol) = vv;
        }
    }
}

extern "C" void kernel_launch(void* const* d_in, const int* in_sizes, int n_in,
                              void* d_out, int out_size, void* d_ws, size_t ws_size,
                              hipStream_t stream) {
    const float* batch_s  = (const float*)d_in[0];
    const float* batch_ro = (const float*)d_in[1];
    float* out = (float*)d_out;

    short* sF  = (short*)d_ws;                  // 2048*256 bf16 = 1 MiB
    short* roF = sF + (size_t)S_ROWS * ROWLEN;  // 8192*256 bf16 = 4 MiB

    const int totalV4 = (S_ROWS + RO_ROWS) * ROWLEN / 4;   // 655360 (exact x256)
    mhd_normalize<<<totalV4 / 256, 256, 0, stream>>>(batch_s, batch_ro, sF, roF);

    // 512 blocks: bit0-2 = XCD/strip, rest = col tile (ro streamed in order)
    mhd_dist<<<(S_ROWS / 256) * (RO_ROWS / 128), 512, 0, stream>>>(sF, roF, out);
}

// Round 12
// 100.631 us; speedup vs baseline: 1.0608x; 1.0608x over previous
//
#include <hip/hip_runtime.h>

#define S_ROWS 2048
#define RO_ROWS 8192
#define HEADS 8
#define HDIM 32
#define ROWLEN 256           // HEADS * HDIM
#define NB_S (S_ROWS / 16)   // 128 fragment-blocks of s
#define NB_RO (RO_ROWS / 16) // 512 fragment-blocks of ro

typedef __attribute__((ext_vector_type(8))) short bf16x8;
typedef __attribute__((ext_vector_type(4))) float f32x4;
typedef __attribute__((ext_vector_type(4))) short s16x4;

__device__ __forceinline__ short f32_to_bf16_rne(float f) {
    union { float f; unsigned u; } v; v.f = f;
    return (short)((v.u + 0x7fffu + ((v.u >> 16) & 1u)) >> 16);
}

// async global->LDS, 16B per lane: LDS dest = wave-uniform base + lane*16
// (HW); global src is per-lane (we add lane*16 at the call site).
__device__ __forceinline__ void gll16(const void* g, void* l) {
    __builtin_amdgcn_global_load_lds(
        (const __attribute__((address_space(1))) unsigned*)g,
        (__attribute__((address_space(3))) unsigned*)l, 16, 0, 0);
}

// Normalize every 32-elem head vector; emit bf16 fragments in LANE-LINEAR
// MFMA order: fragment (h, nb) is 1 KiB where byte offset lane*16 holds the
// 8 bf16 that MFMA lane `lane` consumes (row = lane&15, k = (lane>>4)*8..+7).
// Dist then loads operands as frag_base + lane*16B — fully coalesced 1 KiB
// per wave-instruction (and gll16-stageable as a pure linear copy).
__global__ __launch_bounds__(256) void mhd_normalize(const float* __restrict__ s,
                                                     const float* __restrict__ ro,
                                                     short* __restrict__ sF,
                                                     short* __restrict__ roF) {
    const int v   = blockIdx.x * 256 + threadIdx.x;  // vec4-element id
    const int dg  = v & 7;            // k-elems dg*4 .. dg*4+3
    const int r16 = (v >> 3) & 15;    // row within fragment block
    const int u   = v >> 7;           // (h, nb) chunk id
    const int h   = u & 7;
    const int nb_all = u >> 3;        // 0..639
    const bool isS = nb_all < NB_S;
    const int nb  = isS ? nb_all : nb_all - NB_S;
    const int n   = nb * 16 + r16;    // source row within its tensor

    const float* src = isS ? s : ro;
    f32x4 x = *(const f32x4*)(src + (size_t)n * ROWLEN + h * HDIM + dg * 4);
    float ss = x[0] * x[0] + x[1] * x[1] + x[2] * x[2] + x[3] * x[3];
    ss += __shfl_xor(ss, 1);
    ss += __shfl_xor(ss, 2);
    ss += __shfl_xor(ss, 4);
    const float inv = rsqrtf(ss);
    s16x4 r;
    r[0] = f32_to_bf16_rne(x[0] * inv);
    r[1] = f32_to_bf16_rne(x[1] * inv);
    r[2] = f32_to_bf16_rne(x[2] * inv);
    r[3] = f32_to_bf16_rne(x[3] * inv);

    short* dst = isS ? sF : roF;
    const int NB = isS ? NB_S : NB_RO;
    // lane-linear: lane = (dg>>1)*16 + r16, 16B half = dg&1
    const int lane_in_frag = ((dg >> 1) << 4) + r16;
    const size_t off = ((size_t)(h * NB + nb) << 9) + lane_in_frag * 8 + (dg & 1) * 4;
    *(s16x4*)(dst + off) = r;
}

// TLP-max + LDS-B + streamed-store design:
// Block tile 512x64 (8 waves of 64x64), grid 4x128 = 512 blocks.
// B (64 ro-cols x 8 heads = 32 KiB) staged ONCE into LDS via gll16 ->
// per-iter B reads are conflict-free ds_read_b128, zero global B re-reads.
// VGPR ~56 under __launch_bounds__(512,8) -> 4 blocks/CU = 32 waves/CU
// (2x R10's TLP) to bury load latency.
// Each wave = 2 halves of 32 rows: h-outer within a half (b reused for the
// half's 2 row-chunks), stores issue at 50%/100% of wave life -> the 64 MiB
// write stream drains under compute instead of a terminal burst.
// rowTile = bid&3 is XCD-pinned (s-slice 256 KiB + B 2 MiB L2-resident).
// mfma(b, a): D lane-axis (lane&15) = s-row, reg-axis kg*4+q = ro-col.
// Direct stores: per instr 16 rows x 64B; adjacent j's merge to full
// 128B lines in L2.
__global__ __launch_bounds__(512, 8) void mhd_dist(const short* __restrict__ sF,
                                                   const short* __restrict__ roF,
                                                   float* __restrict__ out) {
    __shared__ short ldsB[32 * 512];          // 32 KiB: frag f = h*4 + jj
    const int lane = threadIdx.x & 63;
    const int wave = threadIdx.x >> 6;        // 0..7 -> rows wave*64
    const int rowTile = blockIdx.x & 3;       // 4 row tiles of 512 (XCD-pinned)
    const int colTile = blockIdx.x >> 2;      // 128 col tiles of 64
    const size_t laneOff = (size_t)lane * 8;  // shorts = lane*16B

    // stage B once: wave w stages head h=w, 4 fragblocks = 4 KiB contiguous
#pragma unroll
    for (int r = 0; r < 4; ++r)
        gll16(roF + (((size_t)(wave * NB_RO + colTile * 4 + r)) << 9) + laneOff,
              &ldsB[(size_t)(wave * 4 + r) << 9]);
    __syncthreads();   // drains gll16 (vmcnt 0) + all waves staged

    const int nbA = rowTile * 32 + wave * 4;  // wave's first s fragment-block
    const int l15 = lane & 15;
    const int kg = lane >> 4;
    float* outW = out + (size_t)(rowTile * 512 + wave * 64) * RO_ROWS
                      + colTile * 64;

#pragma unroll 1
    for (int p = 0; p < 2; ++p) {             // half = 32 rows = 2 chunks
        f32x4 rmax[2][4];
#pragma unroll
        for (int c = 0; c < 2; ++c)
#pragma unroll
            for (int j = 0; j < 4; ++j)
                rmax[c][j] = (f32x4){-3.0e38f, -3.0e38f, -3.0e38f, -3.0e38f};

#pragma unroll 1
        for (int h = 0; h < HEADS; ++h) {
            const short* aCol = sF + (((size_t)(h * NB_S + nbA + p * 2)) << 9) + laneOff;
            const bf16x8 a0 = *(const bf16x8*)(aCol);        // chunk c=0
            const bf16x8 a1 = *(const bf16x8*)(aCol + 512);  // chunk c=1 (+1 KiB)
#pragma unroll
            for (int j = 0; j < 4; ++j) {
                const bf16x8 b = *(const bf16x8*)&ldsB[(((size_t)(h * 4 + j)) << 9) + laneOff];
                f32x4 t0 = {0.f, 0.f, 0.f, 0.f};
                f32x4 t1 = {0.f, 0.f, 0.f, 0.f};
                t0 = __builtin_amdgcn_mfma_f32_16x16x32_bf16(b, a0, t0, 0, 0, 0);
                t1 = __builtin_amdgcn_mfma_f32_16x16x32_bf16(b, a1, t1, 0, 0, 0);
#pragma unroll
                for (int q = 0; q < 4; ++q) {
                    rmax[0][j][q] = fmaxf(rmax[0][j][q], t0[q]);
                    rmax[1][j][q] = fmaxf(rmax[1][j][q], t1[q]);
                }
            }
        }

        // stream this half's 2 chunks: row = p*32 + c*16 + l15,
        // col = j*16 + kg*4 (+q). 8 store instrs, issued mid-kernel.
#pragma unroll
        for (int c = 0; c < 2; ++c)
#pragma unroll
            for (int j = 0; j < 4; ++j)
                *(f32x4*)(outW + (size_t)(p * 32 + c * 16 + l15) * RO_ROWS
                          + j * 16 + kg * 4) = rmax[c][j];
    }
}

extern "C" void kernel_launch(void* const* d_in, const int* in_sizes, int n_in,
                              void* d_out, int out_size, void* d_ws, size_t ws_size,
                              hipStream_t stream) {
    const float* batch_s  = (const float*)d_in[0];
    const float* batch_ro = (const float*)d_in[1];
    float* out = (float*)d_out;

    short* sF  = (short*)d_ws;                  // 2048*256 bf16 = 1 MiB
    short* roF = sF + (size_t)S_ROWS * ROWLEN;  // 8192*256 bf16 = 4 MiB

    const int totalV4 = (S_ROWS + RO_ROWS) * ROWLEN / 4;   // 655360 (exact x256)
    mhd_normalize<<<totalV4 / 256, 256, 0, stream>>>(batch_s, batch_ro, sF, roF);

    // 512 blocks: bit0-1 = row tile (XCD-pinned), bit2+ = col tile
    mhd_dist<<<(S_ROWS / 512) * (RO_ROWS / 64), 512, 0, stream>>>(sF, roF, out);
}